// Round 5
// baseline (281.988 us; speedup 1.0000x reference)
//
#include <hip/hip_runtime.h>
#include <cstdint>

#define M_PTS 8192
#define N_QRY 8192
#define BATCH 4

typedef unsigned long long ull;

// ---------------- helpers ----------------
__device__ __forceinline__ float d2_exact(float qx, float qy, float qz, float q2, float4 p) {
#pragma clang fp contract(off)
  float dot = (qx * p.x + qy * p.y) + qz * p.z;   // reference op order, no fma
  return (q2 + p.w) - 2.0f * dot;
}

__device__ __forceinline__ unsigned flipf(float d) {
  unsigned u = __float_as_uint(d);
  return u ^ ((unsigned)((int)u >> 31) | 0x80000000u);   // order-preserving float->uint
}

__device__ __forceinline__ int lane_prefix(unsigned long long m) {
  return __builtin_amdgcn_mbcnt_hi((unsigned)(m >> 32),
         __builtin_amdgcn_mbcnt_lo((unsigned)m, 0));
}

__device__ __forceinline__ void ld_lds16(const float4* g, float4* l) {
  __builtin_amdgcn_global_load_lds((const __attribute__((address_space(1))) void*)g,
                                   (__attribute__((address_space(3))) void*)l, 16, 0, 0);
}

// Upper bound on the 16th-smallest of the 64 per-lane mins, via ballot bisection.
// Invariant: count(mn <= hi) >= 16 holds from init (hi = wave max -> 64). 10 steps
// give resolution (hi0-lo0)/1024; looseness only ADDS candidates, never drops one.
__device__ __forceinline__ float tau16(float mn) {
  float lo = mn, hi = mn;
#pragma unroll
  for (int j = 1; j < 64; j <<= 1) {
    lo = fminf(lo, __shfl_xor(lo, j));
    hi = fmaxf(hi, __shfl_xor(hi, j));
  }
#pragma unroll
  for (int it = 0; it < 10; it++) {
    float mid = 0.5f * (lo + hi);
    int cnt = __popcll(__ballot(mn <= mid));
    if (cnt >= 16) hi = mid; else lo = mid;   // wave-uniform
  }
  return hi;
}

// Full 64-lane ascending bitonic sort of u64 keys; lane i ends with the i-th
// smallest. Same network/orientation as the R0-verified rank16.
__device__ __forceinline__ ull bsort64(ull v, int lane) {
#pragma unroll
  for (int k = 2; k <= 64; k <<= 1) {
#pragma unroll
    for (int j = k >> 1; j >= 1; j >>= 1) {
      ull o = __shfl_xor(v, j);
      bool keepmin = (((lane & k) == 0) == ((lane & j) == 0));
      ull lo = v < o ? v : o;
      ull hi = v < o ? o : v;
      v = keepmin ? lo : hi;
    }
  }
  return v;
}

// ---------------- K0a: pack (x, y, z, x^2+y^2+z^2) ----------------
__global__ void pack_pts(const float* __restrict__ src, float4* __restrict__ dst, int total) {
#pragma clang fp contract(off)
  int i = blockIdx.x * 256 + threadIdx.x;
  if (i >= total) return;
  int b = i >> 13, m = i & (M_PTS - 1);
  const float* s = src + (size_t)b * 3 * M_PTS;
  float x = s[m], y = s[M_PTS + m], z = s[2 * M_PTS + m];
  float ss = (x * x + y * y) + z * z;   // matches jnp.sum(pts**2, axis=1) order
  dst[i] = make_float4(x, y, z, ss);
}

// ---------------- K0b: transpose local_feat (B,64,M) -> (B,M,64) ----------------
__global__ void transpose_lf(const float* __restrict__ lf, float* __restrict__ lfT) {
  __shared__ float tile[64][65];
  int bb = blockIdx.x >> 7;
  int m0 = (blockIdx.x & 127) << 6;
  int tm = threadIdx.x & 63;
  int tc = threadIdx.x >> 6;
  const float* src = lf + (size_t)bb * 64 * M_PTS;
#pragma unroll
  for (int i = 0; i < 16; i++) {
    int ch = i * 4 + tc;
    tile[ch][tm] = src[(size_t)ch * M_PTS + m0 + tm];
  }
  __syncthreads();
  float* dst = lfT + ((size_t)bb * M_PTS + m0) * 64;
#pragma unroll
  for (int i = 0; i < 16; i++) {
    int mm = i * 4 + tc;
    dst[(size_t)mm * 64 + tm] = tile[tm][mm];
  }
}

// ---------------- K1: exact KNN top-16, 4 queries per wave ----------------
// R5: 4 queries per wave (grid 2048, 16 q/block). Each LDS point read now
// feeds 4 distance chains: ds_read traffic and staging/barrier overhead per
// point-pair are HALVED vs R4. Same monotone prefix tau (seeded on first
// 1024 pts, tightened at 2048/4096 prefixes; stale tau is only looser, never
// drops a true neighbor), same double-buffered 512-pt staging (static
// ping-pong, no dynamic buffer select), same O(1)-sort finalize with exact
// rescore -> output bit-identical to R0-R4. LDS 28.7 KB -> 5 blocks/CU.
__global__ void __launch_bounds__(256, 5) knn_kernel(const float4* __restrict__ pp,
                                                     const float4* __restrict__ qp,
                                                     int* __restrict__ knn_out) {
  __shared__ float4 spts[2][512];        // 16 KB double-buffered point stage
  __shared__ ull cbuf[16][96];           // 12 KB cand buffers (per wave x 4 q; 192 u32 view)
  const int tid = threadIdx.x;
  const int lane = tid & 63;
  const int wave = tid >> 6;
  const int b = blockIdx.x >> 9;                  // 512 blocks per batch
  const int qa = blockIdx.x * 16 + wave * 4;      // this wave's four queries
  const float4* pb = pp + ((size_t)b << 13);

  float4 Q[4];
  float ax[4], ay[4], az[4], mn[4], tau[4];
  int cnt[4];
  unsigned* cq[4];
#pragma unroll
  for (int i = 0; i < 4; i++) {
    Q[i] = qp[qa + i];
    ax[i] = -2.0f * Q[i].x; ay[i] = -2.0f * Q[i].y; az[i] = -2.0f * Q[i].z;
    mn[i] = 3.402823466e38f;
    tau[i] = 0.0f;
    cnt[i] = 0;
    cq[i] = (unsigned*)cbuf[wave * 4 + i];
  }

  auto stage = [&](float4* dst, int s) {
#pragma unroll
    for (int i = 0; i < 2; i++) {
      const float4* g = pb + s * 512 + i * 256 + wave * 64 + lane;
      ld_lds16(g, &dst[i * 256 + wave * 64]);   // wave-uniform LDS base + lane*16
    }
  };

  auto minpass = [&](const float4* sp) {
#pragma unroll
    for (int j = 0; j < 8; j++) {
      float4 p = sp[j * 64 + lane];
#pragma unroll
      for (int i = 0; i < 4; i++)
        mn[i] = fminf(mn[i], __builtin_fmaf(ax[i], p.x, __builtin_fmaf(ay[i], p.y,
                            __builtin_fmaf(az[i], p.z, p.w))));
    }
  };

  auto fused = [&](const float4* sp, unsigned base) {
#pragma unroll
    for (int j = 0; j < 8; j++) {
      float4 p = sp[j * 64 + lane];
      // pin: one ds_read per point, compiler cannot rematerialize per query
      asm volatile("" : "+v"(p.x), "+v"(p.y), "+v"(p.z), "+v"(p.w));
      unsigned idx = base + j * 64 + lane;
#pragma unroll
      for (int i = 0; i < 4; i++) {
        float e = __builtin_fmaf(ax[i], p.x, __builtin_fmaf(ay[i], p.y,
                  __builtin_fmaf(az[i], p.z, p.w)));
        mn[i] = fminf(mn[i], e);
        bool pred = e <= tau[i];
        unsigned long long mask = __ballot(pred);
        if (mask) {                       // wave-uniform; most iters skip here
          int pos = cnt[i] + lane_prefix(mask);
          if (pred && pos < 192) cq[i][pos] = idx;
          cnt[i] += __popcll(mask);
        }
      }
    }
  };

  // ---- prologue: seed tau on first 1024 pts (two-pass over sc0/sc1) ----
  stage(spts[0], 0);
  __syncthreads();                       // sc0 visible
  stage(spts[1], 1);                     // in flight during minpass(sc0)
  minpass(spts[0]);
  __syncthreads();                       // sc1 visible
  minpass(spts[1]);
#pragma unroll
  for (int i = 0; i < 4; i++)
    tau[i] = tau16(mn[i]) + 0.01f;       // margin >> fma-vs-exact divergence
  fused(spts[0], 0);
  fused(spts[1], 512);
  __syncthreads();                       // all waves done reading sc0/sc1
  stage(spts[0], 2);
  __syncthreads();                       // sc2 visible (single true stall)

  // ---- steady state: stage next sub-chunk, compute current, barrier ----
  for (int sb = 2; sb < 16; sb += 2) {
    if (sb + 1 < 16) stage(spts[1], sb + 1);
    fused(spts[0], (unsigned)(sb * 512));
    __syncthreads();                     // drains vmcnt -> buf1 visible; buf0 free
    if (sb + 2 < 16) stage(spts[0], sb + 2);
    fused(spts[1], (unsigned)((sb + 1) * 512));
    if (sb == 2 || sb == 6) {            // tighten tau at 2048/4096 prefixes
#pragma unroll
      for (int i = 0; i < 4; i++)
        tau[i] = fminf(tau[i], tau16(mn[i]) + 0.01f);
    }
    __syncthreads();                     // drains vmcnt -> buf0 visible; buf1 free
  }

  auto finalize = [&](ull* cb, int cntq, int gq,
                      float qx, float qy, float qz, float q2) {
    unsigned* cu = (unsigned*)cb;
    int E = cntq < 192 ? cntq : 192;          // E >= 16 guaranteed by prologue tau
    unsigned i0 = (lane < E) ? cu[lane] : 0u;
    unsigned i1 = (lane + 64 < E) ? cu[lane + 64] : 0u;
    unsigned i2 = (lane + 128 < E) ? cu[lane + 128] : 0u;
    float4 p0 = pb[i0];                       // parallel L2-hit loads
    float4 p1 = pb[i1];
    float4 p2 = pb[i2];
    ull k0 = ~0ull, k1 = ~0ull, k2 = ~0ull;
    if (lane < E)
      k0 = ((ull)flipf(d2_exact(qx, qy, qz, q2, p0)) << 32) | i0;
    if (lane + 64 < E)
      k1 = ((ull)flipf(d2_exact(qx, qy, qz, q2, p1)) << 32) | i1;
    if (lane + 128 < E)
      k2 = ((ull)flipf(d2_exact(qx, qy, qz, q2, p2)) << 32) | i2;
    // lane-min, then T = 16th-smallest lane-min (valid: E>=16 -> lanes 0..15
    // all hold a real k0). Every true top-16 key <= T; keys <= T live only in
    // the 16 lanes whose lane-min <= T -> at most 48 survivors.
    ull ml = k0 < k1 ? k0 : k1;
    if (k2 < ml) ml = k2;
    ull T = __shfl(bsort64(ml, lane), 15);
    // ballot-compact survivors into cb (u64 view; cu reads already consumed)
    int c2 = 0;
    {
      bool pr = k0 <= T; ull m = __ballot(pr);
      int pos = c2 + lane_prefix(m);
      if (pr) cb[pos] = k0;
      c2 += __popcll(m);
    }
    {
      bool pr = k1 <= T; ull m = __ballot(pr);
      int pos = c2 + lane_prefix(m);
      if (pr) cb[pos] = k1;
      c2 += __popcll(m);
    }
    {
      bool pr = k2 <= T; ull m = __ballot(pr);
      int pos = c2 + lane_prefix(m);
      if (pr) cb[pos] = k2;
      c2 += __popcll(m);
    }
    // wave-local RAW: lgkmcnt ordering suffices, no barrier
    ull kk = (lane < c2) ? cb[lane] : ~0ull;
    ull fin = bsort64(kk, lane);
    if (lane < 16) knn_out[(size_t)gq * 16 + lane] = (int)(unsigned)fin;
  };

#pragma unroll
  for (int i = 0; i < 4; i++)
    finalize(cbuf[wave * 4 + i], cnt[i], qa + i, Q[i].x, Q[i].y, Q[i].z, Q[i].w);
}

// ---------------- K2: fused feature pipeline, 16 queries per block ----------------
// lane = channel. w1 row lives in 64 VGPRs per lane (raw weights; BN scale applied
// after accumulation). w1s pinned via empty asm ("+v") so the compiler cannot
// rematerialize the global loads inside the matvec loop.
__global__ void __launch_bounds__(256, 4) feat_kernel(
    const float4* __restrict__ pp, const float4* __restrict__ qp,
    const int* __restrict__ knn, const float* __restrict__ lfT,
    const float* __restrict__ w0, const float* __restrict__ b0,
    const float* __restrict__ g0, const float* __restrict__ be0,
    const float* __restrict__ m0, const float* __restrict__ v0,
    const float* __restrict__ w1, const float* __restrict__ b1,
    const float* __restrict__ g1, const float* __restrict__ be1,
    const float* __restrict__ m1, const float* __restrict__ v1,
    const float* __restrict__ w2, const float* __restrict__ b2,
    float* __restrict__ out) {
  __shared__ float4 relbuf[4][16];
  __shared__ float4 f0v[4][64];
  __shared__ float outbuf[64][17];     // +1 pad breaks write-phase bank conflicts
  const int tid = threadIdx.x;
  const int lane = tid & 63;
  const int wave = tid >> 6;
  const int gq0 = blockIdx.x * 16;
  const int b = gq0 >> 13;

  // BN folds (inline; fp order matches R0's fold_kernel)
  const float inv0 = g0[lane] / sqrtf(v0[lane] + 1e-5f);
  const float w00 = w0[lane * 3 + 0] * inv0;
  const float w01 = w0[lane * 3 + 1] * inv0;
  const float w02 = w0[lane * 3 + 2] * inv0;
  const float bb0 = (b0[lane] - m0[lane]) * inv0 + be0[lane];
  const float inv1 = g1[lane] / sqrtf(v1[lane] + 1e-5f);
  const float bb1 = (b1[lane] - m1[lane]) * inv1 + be1[lane];

  float w1s[64];
#pragma unroll
  for (int i = 0; i < 16; i++) {
    float4 t = ((const float4*)(w1 + (size_t)lane * 64))[i];
    w1s[i * 4 + 0] = t.x; w1s[i * 4 + 1] = t.y;
    w1s[i * 4 + 2] = t.z; w1s[i * 4 + 3] = t.w;
  }
  // Pin each w1 value into a VGPR: compiler can no longer rematerialize the
  // global load inside the matvec loop.
#pragma unroll
  for (int k = 0; k < 64; k++) asm volatile("" : "+v"(w1s[k]));

  const float w2a = w2[lane], w2b = w2[64 + lane];
  const float bias2 = b2[0];
  const float4* pb = pp + ((size_t)b << 13);
  const float* lfb = lfT + (((size_t)b << 13)) * 64;

  for (int qi = 0; qi < 4; qi++) {
    const int gq = gq0 + wave * 4 + qi;
    const float4 q4 = qp[gq];
    int nk = knn[(size_t)gq * 16 + (lane & 15)];
    float4 pk = pb[nk];
    if (lane < 16)
      relbuf[wave][lane] = make_float4(pk.x - q4.x, pk.y - q4.y, pk.z - q4.z, 0.0f);
    // wave-local RAW: lgkmcnt ordering suffices, no barrier

    float g = 0.0f, f0 = 0, f1 = 0, f2 = 0, f3 = 0;
#pragma unroll
    for (int k = 0; k < 16; k++) {
      float4 r = relbuf[wave][k];
      float y = fmaxf(0.0f, w00 * r.x + w01 * r.y + w02 * r.z + bb0);
      g = fmaxf(g, y);
      if (k == 0) f0 = y; else if (k == 1) f1 = y;
      else if (k == 2) f2 = y; else if (k == 3) f3 = y;
    }
    f0v[wave][lane] = make_float4(f0, f1, f2, f3);

    float a0 = 0, a1 = 0, a2 = 0, a3 = 0;
#pragma unroll
    for (int c2 = 0; c2 < 64; c2++) {
      float w = w1s[c2];                 // register (pinned, compile-time index)
      float4 fb = f0v[wave][c2];         // LDS broadcast
      a0 = fmaf(w, fb.x, a0); a1 = fmaf(w, fb.y, a1);
      a2 = fmaf(w, fb.z, a2); a3 = fmaf(w, fb.w, a3);
    }
    float r0 = fmaxf(0.0f, fmaf(a0, inv1, bb1));
    float r1 = fmaxf(0.0f, fmaf(a1, inv1, bb1));
    float r2 = fmaxf(0.0f, fmaf(a2, inv1, bb1));
    float r3 = fmaxf(0.0f, fmaf(a3, inv1, bb1));

    int i0 = __shfl(nk, 0), i1 = __shfl(nk, 1), i2 = __shfl(nk, 2), i3 = __shfl(nk, 3);
    float p0 = lfb[(size_t)i0 * 64 + lane];
    float p1 = lfb[(size_t)i1 * 64 + lane];
    float p2 = lfb[(size_t)i2 * 64 + lane];
    float p3 = lfb[(size_t)i3 * 64 + lane];

    float s0 = w2a * r0, s1 = w2a * r1, s2 = w2a * r2, s3 = w2a * r3, tg = w2b * g;
#pragma unroll
    for (int j = 1; j < 64; j <<= 1) {
      s0 += __shfl_xor(s0, j);
      s1 += __shfl_xor(s1, j);
      s2 += __shfl_xor(s2, j);
      s3 += __shfl_xor(s3, j);
      tg += __shfl_xor(tg, j);
    }
    float wk0 = 1.0f / (1.0f + __expf(-(s0 + tg + bias2)));
    float wk1 = 1.0f / (1.0f + __expf(-(s1 + tg + bias2)));
    float wk2 = 1.0f / (1.0f + __expf(-(s2 + tg + bias2)));
    float wk3 = 1.0f / (1.0f + __expf(-(s3 + tg + bias2)));

    float oc = ((1.0f - wk0) * r0 + wk0 * p0)
             + ((1.0f - wk1) * r1 + wk1 * p1)
             + ((1.0f - wk2) * r2 + wk2 * p2)
             + ((1.0f - wk3) * r3 + wk3 * p3);
    outbuf[lane][wave * 4 + qi] = oc;
  }
  __syncthreads();

  // coalesced output: thread t -> channel c = t>>2, 4 queries via float4
  int c = tid >> 2, j = tid & 3;
  float4 o4 = make_float4(outbuf[c][j * 4 + 0], outbuf[c][j * 4 + 1],
                          outbuf[c][j * 4 + 2], outbuf[c][j * 4 + 3]);
  *(float4*)(out + (((size_t)(b * 64 + c)) << 13) + (gq0 & (N_QRY - 1)) + j * 4) = o4;
}

extern "C" void kernel_launch(void* const* d_in, const int* in_sizes, int n_in,
                              void* d_out, int out_size, void* d_ws, size_t ws_size,
                              hipStream_t stream) {
  (void)in_sizes; (void)n_in; (void)out_size; (void)ws_size;
  const float* original_pts = (const float*)d_in[0];
  const float* query_pts   = (const float*)d_in[1];
  const float* local_feat  = (const float*)d_in[2];
  const float* w0 = (const float*)d_in[3];
  const float* b0 = (const float*)d_in[4];
  const float* g0 = (const float*)d_in[5];
  const float* be0 = (const float*)d_in[6];
  const float* m0 = (const float*)d_in[7];
  const float* v0 = (const float*)d_in[8];
  const float* w1 = (const float*)d_in[9];
  const float* b1 = (const float*)d_in[10];
  const float* g1 = (const float*)d_in[11];
  const float* be1 = (const float*)d_in[12];
  const float* m1 = (const float*)d_in[13];
  const float* v1 = (const float*)d_in[14];
  const float* w2 = (const float*)d_in[15];
  const float* b2 = (const float*)d_in[16];
  float* out = (float*)d_out;

  // workspace layout (16B aligned), total ~11.5 MB
  char* ws = (char*)d_ws;
  float4* pp  = (float4*)(ws);                 // 512 KB
  float4* qp  = (float4*)(ws + 524288);        // 512 KB
  float*  lfT = (float*)(ws + 1048576);        // 8 MB
  int*    knn = (int*)(ws + 9437184);          // 2 MB

  pack_pts<<<128, 256, 0, stream>>>(original_pts, pp, BATCH * M_PTS);
  pack_pts<<<128, 256, 0, stream>>>(query_pts, qp, BATCH * N_QRY);
  transpose_lf<<<512, 256, 0, stream>>>(local_feat, lfT);
  knn_kernel<<<2048, 256, 0, stream>>>(pp, qp, knn);
  feat_kernel<<<2048, 256, 0, stream>>>(pp, qp, knn, lfT,
                                        w0, b0, g0, be0, m0, v0,
                                        w1, b1, g1, be1, m1, v1,
                                        w2, b2, out);
}

// Round 6
// 273.802 us; speedup vs baseline: 1.0299x; 1.0299x over previous
//
#include <hip/hip_runtime.h>
#include <cstdint>

#define M_PTS 8192
#define N_QRY 8192
#define BATCH 4

typedef unsigned long long ull;

// ---------------- helpers ----------------
__device__ __forceinline__ float d2_exact(float qx, float qy, float qz, float q2, float4 p) {
#pragma clang fp contract(off)
  float dot = (qx * p.x + qy * p.y) + qz * p.z;   // reference op order, no fma
  return (q2 + p.w) - 2.0f * dot;
}

__device__ __forceinline__ unsigned flipf(float d) {
  unsigned u = __float_as_uint(d);
  return u ^ ((unsigned)((int)u >> 31) | 0x80000000u);   // order-preserving float->uint
}

__device__ __forceinline__ int lane_prefix(unsigned long long m) {
  return __builtin_amdgcn_mbcnt_hi((unsigned)(m >> 32),
         __builtin_amdgcn_mbcnt_lo((unsigned)m, 0));
}

__device__ __forceinline__ void ld_lds16(const float4* g, float4* l) {
  __builtin_amdgcn_global_load_lds((const __attribute__((address_space(1))) void*)g,
                                   (__attribute__((address_space(3))) void*)l, 16, 0, 0);
}

// Upper bound on the 16th-smallest of the 64 per-lane mins, via ballot bisection.
// Invariant: count(mn <= hi) >= 16 holds from init (hi = wave max -> 64). 10 steps
// give resolution (hi0-lo0)/1024; looseness only ADDS candidates, never drops one.
__device__ __forceinline__ float tau16(float mn) {
  float lo = mn, hi = mn;
#pragma unroll
  for (int j = 1; j < 64; j <<= 1) {
    lo = fminf(lo, __shfl_xor(lo, j));
    hi = fmaxf(hi, __shfl_xor(hi, j));
  }
#pragma unroll
  for (int it = 0; it < 10; it++) {
    float mid = 0.5f * (lo + hi);
    int cnt = __popcll(__ballot(mn <= mid));
    if (cnt >= 16) hi = mid; else lo = mid;   // wave-uniform
  }
  return hi;
}

// Full 64-lane ascending bitonic sort of u64 keys; lane i ends with the i-th
// smallest. Same network/orientation as the R0-verified rank16.
__device__ __forceinline__ ull bsort64(ull v, int lane) {
#pragma unroll
  for (int k = 2; k <= 64; k <<= 1) {
#pragma unroll
    for (int j = k >> 1; j >= 1; j >>= 1) {
      ull o = __shfl_xor(v, j);
      bool keepmin = (((lane & k) == 0) == ((lane & j) == 0));
      ull lo = v < o ? v : o;
      ull hi = v < o ? o : v;
      v = keepmin ? lo : hi;
    }
  }
  return v;
}

// ---------------- K0a: pack (x, y, z, x^2+y^2+z^2) ----------------
__global__ void pack_pts(const float* __restrict__ src, float4* __restrict__ dst, int total) {
#pragma clang fp contract(off)
  int i = blockIdx.x * 256 + threadIdx.x;
  if (i >= total) return;
  int b = i >> 13, m = i & (M_PTS - 1);
  const float* s = src + (size_t)b * 3 * M_PTS;
  float x = s[m], y = s[M_PTS + m], z = s[2 * M_PTS + m];
  float ss = (x * x + y * y) + z * z;   // matches jnp.sum(pts**2, axis=1) order
  dst[i] = make_float4(x, y, z, ss);
}

// ---------------- K0b: transpose local_feat (B,64,M) -> (B,M,64) ----------------
__global__ void transpose_lf(const float* __restrict__ lf, float* __restrict__ lfT) {
  __shared__ float tile[64][65];
  int bb = blockIdx.x >> 7;
  int m0 = (blockIdx.x & 127) << 6;
  int tm = threadIdx.x & 63;
  int tc = threadIdx.x >> 6;
  const float* src = lf + (size_t)bb * 64 * M_PTS;
#pragma unroll
  for (int i = 0; i < 16; i++) {
    int ch = i * 4 + tc;
    tile[ch][tm] = src[(size_t)ch * M_PTS + m0 + tm];
  }
  __syncthreads();
  float* dst = lfT + ((size_t)bb * M_PTS + m0) * 64;
#pragma unroll
  for (int i = 0; i < 16; i++) {
    int mm = i * 4 + tc;
    dst[(size_t)mm * 64 + tm] = tile[tm][mm];
  }
}

// ---------------- K1: exact KNN top-16, 4 queries per wave ----------------
// R6: same plan as R5 (4 q/wave: each LDS point read feeds 4 distance chains,
// halving ds_read + staging + barrier overhead per point-pair vs R4) but with
// ALL per-query state as explicit scalars and the hot path as macros.
// R5's arrays captured by-ref in lambdas defeated SROA -> scratch spill
// (WRITE_SIZE 69 MB, FETCH +29 MB, VALUBusy 43%). Scalars + straight-line
// code make mem2reg trivial. Monotone prefix tau + dbuf staging + O(1)-sort
// finalize with exact rescore unchanged -> output bit-identical to R0-R4.
// LDS 28.7 KB -> 5 blocks/CU.
__global__ void __launch_bounds__(256, 5) knn_kernel(const float4* __restrict__ pp,
                                                     const float4* __restrict__ qp,
                                                     int* __restrict__ knn_out) {
  __shared__ float4 spts[2][512];        // 16 KB double-buffered point stage
  __shared__ ull cbuf[16][96];           // 12 KB cand buffers (per wave x 4 q)
  const int tid = threadIdx.x;
  const int lane = tid & 63;
  const int wave = tid >> 6;
  const int b = blockIdx.x >> 9;                  // 512 blocks per batch
  const int qa = blockIdx.x * 16 + wave * 4;      // this wave's four queries
  const float4* pb = pp + ((size_t)b << 13);

  float ax0, ay0, az0, ax1, ay1, az1, ax2, ay2, az2, ax3, ay3, az3;
  {
    float4 t0 = qp[qa + 0], t1 = qp[qa + 1], t2 = qp[qa + 2], t3 = qp[qa + 3];
    ax0 = -2.0f * t0.x; ay0 = -2.0f * t0.y; az0 = -2.0f * t0.z;
    ax1 = -2.0f * t1.x; ay1 = -2.0f * t1.y; az1 = -2.0f * t1.z;
    ax2 = -2.0f * t2.x; ay2 = -2.0f * t2.y; az2 = -2.0f * t2.z;
    ax3 = -2.0f * t3.x; ay3 = -2.0f * t3.y; az3 = -2.0f * t3.z;
  }
  float mn0 = 3.402823466e38f, mn1 = mn0, mn2 = mn0, mn3 = mn0;
  float tau0 = 0.0f, tau1 = 0.0f, tau2 = 0.0f, tau3 = 0.0f;
  int cnt0 = 0, cnt1 = 0, cnt2 = 0, cnt3 = 0;
  ull* cb0 = cbuf[wave * 4 + 0];   // wave-uniform -> SGPR
  ull* cb1 = cbuf[wave * 4 + 1];
  ull* cb2 = cbuf[wave * 4 + 2];
  ull* cb3 = cbuf[wave * 4 + 3];

#define STAGE(dbuf, s) do {                                                  \
    ld_lds16(pb + (s) * 512 + 0 * 256 + wave * 64 + lane,                    \
             &spts[dbuf][0 * 256 + wave * 64]);                              \
    ld_lds16(pb + (s) * 512 + 1 * 256 + wave * 64 + lane,                    \
             &spts[dbuf][1 * 256 + wave * 64]);                              \
  } while (0)

#define DIST(e, p, axq, ayq, azq)                                            \
    float e = __builtin_fmaf(axq, p.x, __builtin_fmaf(ayq, p.y,              \
              __builtin_fmaf(azq, p.z, p.w)))

#define MINPASS(dbuf) do {                                                   \
    _Pragma("unroll")                                                        \
    for (int j = 0; j < 8; j++) {                                            \
      float4 p = spts[dbuf][j * 64 + lane];                                  \
      DIST(e0, p, ax0, ay0, az0); mn0 = fminf(mn0, e0);                      \
      DIST(e1, p, ax1, ay1, az1); mn1 = fminf(mn1, e1);                      \
      DIST(e2, p, ax2, ay2, az2); mn2 = fminf(mn2, e2);                      \
      DIST(e3, p, ax3, ay3, az3); mn3 = fminf(mn3, e3);                      \
    }                                                                        \
  } while (0)

#define COLLECT(e, tauq, cntq, cbq, idx) do {                                \
    bool pred = (e) <= (tauq);                                               \
    ull mask = __ballot(pred);                                               \
    if (mask) {                          /* wave-uniform; most iters skip */ \
      int pos = (cntq) + lane_prefix(mask);                                  \
      if (pred && pos < 192) ((unsigned*)(cbq))[pos] = (idx);                \
      (cntq) += __popcll(mask);                                              \
    }                                                                        \
  } while (0)

#define FUSED(dbuf, base) do {                                               \
    _Pragma("unroll")                                                        \
    for (int j = 0; j < 8; j++) {                                            \
      float4 p = spts[dbuf][j * 64 + lane];                                  \
      asm volatile("" : "+v"(p.x), "+v"(p.y), "+v"(p.z), "+v"(p.w));         \
      unsigned idx = (base) + j * 64 + lane;                                 \
      DIST(e0, p, ax0, ay0, az0); mn0 = fminf(mn0, e0);                      \
      COLLECT(e0, tau0, cnt0, cb0, idx);                                     \
      DIST(e1, p, ax1, ay1, az1); mn1 = fminf(mn1, e1);                      \
      COLLECT(e1, tau1, cnt1, cb1, idx);                                     \
      DIST(e2, p, ax2, ay2, az2); mn2 = fminf(mn2, e2);                      \
      COLLECT(e2, tau2, cnt2, cb2, idx);                                     \
      DIST(e3, p, ax3, ay3, az3); mn3 = fminf(mn3, e3);                      \
      COLLECT(e3, tau3, cnt3, cb3, idx);                                     \
    }                                                                        \
  } while (0)

  // ---- prologue: seed tau on first 1024 pts (two-pass over sc0/sc1) ----
  STAGE(0, 0);
  __syncthreads();                       // sc0 visible
  STAGE(1, 1);                           // in flight during minpass(sc0)
  MINPASS(0);
  __syncthreads();                       // sc1 visible
  MINPASS(1);
  tau0 = tau16(mn0) + 0.01f;             // margin >> fma-vs-exact divergence
  tau1 = tau16(mn1) + 0.01f;
  tau2 = tau16(mn2) + 0.01f;
  tau3 = tau16(mn3) + 0.01f;
  FUSED(0, 0u);
  FUSED(1, 512u);
  __syncthreads();                       // all waves done reading sc0/sc1
  STAGE(0, 2);
  __syncthreads();                       // sc2 visible (single true stall)

  // ---- steady state: stage next sub-chunk, compute current, barrier ----
  for (int sb = 2; sb < 16; sb += 2) {
    if (sb + 1 < 16) STAGE(1, sb + 1);
    FUSED(0, (unsigned)(sb * 512));
    __syncthreads();                     // drains vmcnt -> buf1 visible; buf0 free
    if (sb + 2 < 16) STAGE(0, sb + 2);
    FUSED(1, (unsigned)((sb + 1) * 512));
    if (sb == 2 || sb == 6) {            // tighten tau at 2048/4096 prefixes
      tau0 = fminf(tau0, tau16(mn0) + 0.01f);
      tau1 = fminf(tau1, tau16(mn1) + 0.01f);
      tau2 = fminf(tau2, tau16(mn2) + 0.01f);
      tau3 = fminf(tau3, tau16(mn3) + 0.01f);
    }
    __syncthreads();                     // drains vmcnt -> buf0 visible; buf1 free
  }

  auto finalize = [&](ull* cb, int cntq, int gq) {
    float4 q4 = qp[gq];                       // reload (L2 hit) - not kept live
    float qx = q4.x, qy = q4.y, qz = q4.z, q2 = q4.w;
    unsigned* cu = (unsigned*)cb;
    int E = cntq < 192 ? cntq : 192;          // E >= 16 guaranteed by prologue tau
    unsigned i0 = (lane < E) ? cu[lane] : 0u;
    unsigned i1 = (lane + 64 < E) ? cu[lane + 64] : 0u;
    unsigned i2 = (lane + 128 < E) ? cu[lane + 128] : 0u;
    float4 p0 = pb[i0];                       // parallel L2-hit loads
    float4 p1 = pb[i1];
    float4 p2 = pb[i2];
    ull k0 = ~0ull, k1 = ~0ull, k2 = ~0ull;
    if (lane < E)
      k0 = ((ull)flipf(d2_exact(qx, qy, qz, q2, p0)) << 32) | i0;
    if (lane + 64 < E)
      k1 = ((ull)flipf(d2_exact(qx, qy, qz, q2, p1)) << 32) | i1;
    if (lane + 128 < E)
      k2 = ((ull)flipf(d2_exact(qx, qy, qz, q2, p2)) << 32) | i2;
    // lane-min, then T = 16th-smallest lane-min (valid: E>=16 -> lanes 0..15
    // all hold a real k0). Every true top-16 key <= T; keys <= T live only in
    // the 16 lanes whose lane-min <= T -> at most 48 survivors.
    ull ml = k0 < k1 ? k0 : k1;
    if (k2 < ml) ml = k2;
    ull T = __shfl(bsort64(ml, lane), 15);
    // ballot-compact survivors into cb (u64 view; cu reads already consumed)
    int c2 = 0;
    {
      bool pr = k0 <= T; ull m = __ballot(pr);
      int pos = c2 + lane_prefix(m);
      if (pr) cb[pos] = k0;
      c2 += __popcll(m);
    }
    {
      bool pr = k1 <= T; ull m = __ballot(pr);
      int pos = c2 + lane_prefix(m);
      if (pr) cb[pos] = k1;
      c2 += __popcll(m);
    }
    {
      bool pr = k2 <= T; ull m = __ballot(pr);
      int pos = c2 + lane_prefix(m);
      if (pr) cb[pos] = k2;
      c2 += __popcll(m);
    }
    // wave-local RAW: lgkmcnt ordering suffices, no barrier
    ull kk = (lane < c2) ? cb[lane] : ~0ull;
    ull fin = bsort64(kk, lane);
    if (lane < 16) knn_out[(size_t)gq * 16 + lane] = (int)(unsigned)fin;
  };

  finalize(cb0, cnt0, qa + 0);
  finalize(cb1, cnt1, qa + 1);
  finalize(cb2, cnt2, qa + 2);
  finalize(cb3, cnt3, qa + 3);
}

// ---------------- K2: fused feature pipeline, 16 queries per block ----------------
// lane = channel. w1 row lives in 64 VGPRs per lane (raw weights; BN scale applied
// after accumulation). w1s pinned via empty asm ("+v") so the compiler cannot
// rematerialize the global loads inside the matvec loop.
__global__ void __launch_bounds__(256, 4) feat_kernel(
    const float4* __restrict__ pp, const float4* __restrict__ qp,
    const int* __restrict__ knn, const float* __restrict__ lfT,
    const float* __restrict__ w0, const float* __restrict__ b0,
    const float* __restrict__ g0, const float* __restrict__ be0,
    const float* __restrict__ m0, const float* __restrict__ v0,
    const float* __restrict__ w1, const float* __restrict__ b1,
    const float* __restrict__ g1, const float* __restrict__ be1,
    const float* __restrict__ m1, const float* __restrict__ v1,
    const float* __restrict__ w2, const float* __restrict__ b2,
    float* __restrict__ out) {
  __shared__ float4 relbuf[4][16];
  __shared__ float4 f0v[4][64];
  __shared__ float outbuf[64][17];     // +1 pad breaks write-phase bank conflicts
  const int tid = threadIdx.x;
  const int lane = tid & 63;
  const int wave = tid >> 6;
  const int gq0 = blockIdx.x * 16;
  const int b = gq0 >> 13;

  // BN folds (inline; fp order matches R0's fold_kernel)
  const float inv0 = g0[lane] / sqrtf(v0[lane] + 1e-5f);
  const float w00 = w0[lane * 3 + 0] * inv0;
  const float w01 = w0[lane * 3 + 1] * inv0;
  const float w02 = w0[lane * 3 + 2] * inv0;
  const float bb0 = (b0[lane] - m0[lane]) * inv0 + be0[lane];
  const float inv1 = g1[lane] / sqrtf(v1[lane] + 1e-5f);
  const float bb1 = (b1[lane] - m1[lane]) * inv1 + be1[lane];

  float w1s[64];
#pragma unroll
  for (int i = 0; i < 16; i++) {
    float4 t = ((const float4*)(w1 + (size_t)lane * 64))[i];
    w1s[i * 4 + 0] = t.x; w1s[i * 4 + 1] = t.y;
    w1s[i * 4 + 2] = t.z; w1s[i * 4 + 3] = t.w;
  }
  // Pin each w1 value into a VGPR: compiler can no longer rematerialize the
  // global load inside the matvec loop.
#pragma unroll
  for (int k = 0; k < 64; k++) asm volatile("" : "+v"(w1s[k]));

  const float w2a = w2[lane], w2b = w2[64 + lane];
  const float bias2 = b2[0];
  const float4* pb = pp + ((size_t)b << 13);
  const float* lfb = lfT + (((size_t)b << 13)) * 64;

  for (int qi = 0; qi < 4; qi++) {
    const int gq = gq0 + wave * 4 + qi;
    const float4 q4 = qp[gq];
    int nk = knn[(size_t)gq * 16 + (lane & 15)];
    float4 pk = pb[nk];
    if (lane < 16)
      relbuf[wave][lane] = make_float4(pk.x - q4.x, pk.y - q4.y, pk.z - q4.z, 0.0f);
    // wave-local RAW: lgkmcnt ordering suffices, no barrier

    float g = 0.0f, f0 = 0, f1 = 0, f2 = 0, f3 = 0;
#pragma unroll
    for (int k = 0; k < 16; k++) {
      float4 r = relbuf[wave][k];
      float y = fmaxf(0.0f, w00 * r.x + w01 * r.y + w02 * r.z + bb0);
      g = fmaxf(g, y);
      if (k == 0) f0 = y; else if (k == 1) f1 = y;
      else if (k == 2) f2 = y; else if (k == 3) f3 = y;
    }
    f0v[wave][lane] = make_float4(f0, f1, f2, f3);

    float a0 = 0, a1 = 0, a2 = 0, a3 = 0;
#pragma unroll
    for (int c2 = 0; c2 < 64; c2++) {
      float w = w1s[c2];                 // register (pinned, compile-time index)
      float4 fb = f0v[wave][c2];         // LDS broadcast
      a0 = fmaf(w, fb.x, a0); a1 = fmaf(w, fb.y, a1);
      a2 = fmaf(w, fb.z, a2); a3 = fmaf(w, fb.w, a3);
    }
    float r0 = fmaxf(0.0f, fmaf(a0, inv1, bb1));
    float r1 = fmaxf(0.0f, fmaf(a1, inv1, bb1));
    float r2 = fmaxf(0.0f, fmaf(a2, inv1, bb1));
    float r3 = fmaxf(0.0f, fmaf(a3, inv1, bb1));

    int i0 = __shfl(nk, 0), i1 = __shfl(nk, 1), i2 = __shfl(nk, 2), i3 = __shfl(nk, 3);
    float p0 = lfb[(size_t)i0 * 64 + lane];
    float p1 = lfb[(size_t)i1 * 64 + lane];
    float p2 = lfb[(size_t)i2 * 64 + lane];
    float p3 = lfb[(size_t)i3 * 64 + lane];

    float s0 = w2a * r0, s1 = w2a * r1, s2 = w2a * r2, s3 = w2a * r3, tg = w2b * g;
#pragma unroll
    for (int j = 1; j < 64; j <<= 1) {
      s0 += __shfl_xor(s0, j);
      s1 += __shfl_xor(s1, j);
      s2 += __shfl_xor(s2, j);
      s3 += __shfl_xor(s3, j);
      tg += __shfl_xor(tg, j);
    }
    float wk0 = 1.0f / (1.0f + __expf(-(s0 + tg + bias2)));
    float wk1 = 1.0f / (1.0f + __expf(-(s1 + tg + bias2)));
    float wk2 = 1.0f / (1.0f + __expf(-(s2 + tg + bias2)));
    float wk3 = 1.0f / (1.0f + __expf(-(s3 + tg + bias2)));

    float oc = ((1.0f - wk0) * r0 + wk0 * p0)
             + ((1.0f - wk1) * r1 + wk1 * p1)
             + ((1.0f - wk2) * r2 + wk2 * p2)
             + ((1.0f - wk3) * r3 + wk3 * p3);
    outbuf[lane][wave * 4 + qi] = oc;
  }
  __syncthreads();

  // coalesced output: thread t -> channel c = t>>2, 4 queries via float4
  int c = tid >> 2, j = tid & 3;
  float4 o4 = make_float4(outbuf[c][j * 4 + 0], outbuf[c][j * 4 + 1],
                          outbuf[c][j * 4 + 2], outbuf[c][j * 4 + 3]);
  *(float4*)(out + (((size_t)(b * 64 + c)) << 13) + (gq0 & (N_QRY - 1)) + j * 4) = o4;
}

extern "C" void kernel_launch(void* const* d_in, const int* in_sizes, int n_in,
                              void* d_out, int out_size, void* d_ws, size_t ws_size,
                              hipStream_t stream) {
  (void)in_sizes; (void)n_in; (void)out_size; (void)ws_size;
  const float* original_pts = (const float*)d_in[0];
  const float* query_pts   = (const float*)d_in[1];
  const float* local_feat  = (const float*)d_in[2];
  const float* w0 = (const float*)d_in[3];
  const float* b0 = (const float*)d_in[4];
  const float* g0 = (const float*)d_in[5];
  const float* be0 = (const float*)d_in[6];
  const float* m0 = (const float*)d_in[7];
  const float* v0 = (const float*)d_in[8];
  const float* w1 = (const float*)d_in[9];
  const float* b1 = (const float*)d_in[10];
  const float* g1 = (const float*)d_in[11];
  const float* be1 = (const float*)d_in[12];
  const float* m1 = (const float*)d_in[13];
  const float* v1 = (const float*)d_in[14];
  const float* w2 = (const float*)d_in[15];
  const float* b2 = (const float*)d_in[16];
  float* out = (float*)d_out;

  // workspace layout (16B aligned), total ~11.5 MB
  char* ws = (char*)d_ws;
  float4* pp  = (float4*)(ws);                 // 512 KB
  float4* qp  = (float4*)(ws + 524288);        // 512 KB
  float*  lfT = (float*)(ws + 1048576);        // 8 MB
  int*    knn = (int*)(ws + 9437184);          // 2 MB

  pack_pts<<<128, 256, 0, stream>>>(original_pts, pp, BATCH * M_PTS);
  pack_pts<<<128, 256, 0, stream>>>(query_pts, qp, BATCH * N_QRY);
  transpose_lf<<<512, 256, 0, stream>>>(local_feat, lfT);
  knn_kernel<<<2048, 256, 0, stream>>>(pp, qp, knn);
  feat_kernel<<<2048, 256, 0, stream>>>(pp, qp, knn, lfT,
                                        w0, b0, g0, be0, m0, v0,
                                        w1, b1, g1, be1, m1, v1,
                                        w2, b2, out);
}

// Round 7
// 255.247 us; speedup vs baseline: 1.1048x; 1.0727x over previous
//
#include <hip/hip_runtime.h>
#include <cstdint>

#define M_PTS 8192
#define N_QRY 8192
#define BATCH 4

typedef unsigned long long ull;

// ---------------- helpers ----------------
__device__ __forceinline__ float d2_exact(float qx, float qy, float qz, float q2, float4 p) {
#pragma clang fp contract(off)
  float dot = (qx * p.x + qy * p.y) + qz * p.z;   // reference op order, no fma
  return (q2 + p.w) - 2.0f * dot;
}

__device__ __forceinline__ unsigned flipf(float d) {
  unsigned u = __float_as_uint(d);
  return u ^ ((unsigned)((int)u >> 31) | 0x80000000u);   // order-preserving float->uint
}

__device__ __forceinline__ int lane_prefix(unsigned long long m) {
  return __builtin_amdgcn_mbcnt_hi((unsigned)(m >> 32),
         __builtin_amdgcn_mbcnt_lo((unsigned)m, 0));
}

__device__ __forceinline__ void ld_lds16(const float4* g, float4* l) {
  __builtin_amdgcn_global_load_lds((const __attribute__((address_space(1))) void*)g,
                                   (__attribute__((address_space(3))) void*)l, 16, 0, 0);
}

// Upper bound on the 16th-smallest of the 64 per-lane mins, via ballot bisection.
// Invariant: count(mn <= hi) >= 16 holds from init (hi = wave max -> 64). 10 steps
// give resolution (hi0-lo0)/1024; looseness only ADDS candidates, never drops one.
__device__ __forceinline__ float tau16(float mn) {
  float lo = mn, hi = mn;
#pragma unroll
  for (int j = 1; j < 64; j <<= 1) {
    lo = fminf(lo, __shfl_xor(lo, j));
    hi = fmaxf(hi, __shfl_xor(hi, j));
  }
#pragma unroll
  for (int it = 0; it < 10; it++) {
    float mid = 0.5f * (lo + hi);
    int cnt = __popcll(__ballot(mn <= mid));
    if (cnt >= 16) hi = mid; else lo = mid;   // wave-uniform
  }
  return hi;
}

// Full 64-lane ascending bitonic sort of u64 keys; lane i ends with the i-th
// smallest. Same network/orientation as the R0-verified rank16.
__device__ __forceinline__ ull bsort64(ull v, int lane) {
#pragma unroll
  for (int k = 2; k <= 64; k <<= 1) {
#pragma unroll
    for (int j = k >> 1; j >= 1; j >>= 1) {
      ull o = __shfl_xor(v, j);
      bool keepmin = (((lane & k) == 0) == ((lane & j) == 0));
      ull lo = v < o ? v : o;
      ull hi = v < o ? o : v;
      v = keepmin ? lo : hi;
    }
  }
  return v;
}

// ---------------- K0a: pack (x, y, z, x^2+y^2+z^2) ----------------
__global__ void pack_pts(const float* __restrict__ src, float4* __restrict__ dst, int total) {
#pragma clang fp contract(off)
  int i = blockIdx.x * 256 + threadIdx.x;
  if (i >= total) return;
  int b = i >> 13, m = i & (M_PTS - 1);
  const float* s = src + (size_t)b * 3 * M_PTS;
  float x = s[m], y = s[M_PTS + m], z = s[2 * M_PTS + m];
  float ss = (x * x + y * y) + z * z;   // matches jnp.sum(pts**2, axis=1) order
  dst[i] = make_float4(x, y, z, ss);
}

// ---------------- K0b: transpose local_feat (B,64,M) -> (B,M,64) ----------------
__global__ void transpose_lf(const float* __restrict__ lf, float* __restrict__ lfT) {
  __shared__ float tile[64][65];
  int bb = blockIdx.x >> 7;
  int m0 = (blockIdx.x & 127) << 6;
  int tm = threadIdx.x & 63;
  int tc = threadIdx.x >> 6;
  const float* src = lf + (size_t)bb * 64 * M_PTS;
#pragma unroll
  for (int i = 0; i < 16; i++) {
    int ch = i * 4 + tc;
    tile[ch][tm] = src[(size_t)ch * M_PTS + m0 + tm];
  }
  __syncthreads();
  float* dst = lfT + ((size_t)bb * M_PTS + m0) * 64;
#pragma unroll
  for (int i = 0; i < 16; i++) {
    int mm = i * 4 + tc;
    dst[(size_t)mm * 64 + tm] = tile[tm][mm];
  }
}

// ---------------- K1: exact KNN top-16, 2 queries per wave ----------------
// R7: exact revert to the R4 structure (measured 123.7 us, VGPR 36, zero
// scratch). R5/R6 proved the 4-query variant's ~60-value live set exceeds
// the allocator's chosen budget and spills to scratch (WRITE_SIZE 69/35 MB).
// R4: double-buffered 512-pt sub-chunk staging (prefetch covers the barrier's
// vmcnt drain), monotone prefix tau (seeded on first 1024 pts, tightened at
// 2048/4096/6144 prefixes; stale tau only ADDS candidates), O(1)-sort
// finalize: lane-min -> 64-lane bitonic -> T = 16th-smallest lane-min ->
// ballot-compact (<=48 survivors) -> second bitonic -> lanes 0..15 emit.
// Exact-rescore keys -> output bit-identical to R0.
__global__ void __launch_bounds__(256, 7) knn_kernel(const float4* __restrict__ pp,
                                                     const float4* __restrict__ qp,
                                                     int* __restrict__ knn_out) {
  __shared__ float4 spts[2][512];        // 16 KB double-buffered point stage
  __shared__ ull cbuf[8][96];            // 6 KB cand buffers (per wave x 2 q; 192 u32 view)
  const int tid = threadIdx.x;
  const int lane = tid & 63;
  const int wave = tid >> 6;
  const int b = blockIdx.x >> 10;                 // 1024 blocks per batch
  const int qa = blockIdx.x * 8 + wave * 2;       // this wave's two queries
  const float4* pb = pp + ((size_t)b << 13);

  const float4 A4 = qp[qa];
  const float4 B4 = qp[qa + 1];
  const float axA = -2.0f * A4.x, ayA = -2.0f * A4.y, azA = -2.0f * A4.z;
  const float axB = -2.0f * B4.x, ayB = -2.0f * B4.y, azB = -2.0f * B4.z;

  int cntA = 0, cntB = 0;
  unsigned* cqA = (unsigned*)cbuf[wave * 2 + 0];
  unsigned* cqB = (unsigned*)cbuf[wave * 2 + 1];

  float mnA = 3.402823466e38f, mnB = 3.402823466e38f;
  float tauA = 0.0f, tauB = 0.0f;

  auto stage = [&](float4* dst, int s) {
#pragma unroll
    for (int i = 0; i < 2; i++) {
      const float4* g = pb + s * 512 + i * 256 + wave * 64 + lane;
      ld_lds16(g, &dst[i * 256 + wave * 64]);   // wave-uniform LDS base + lane*16
    }
  };

  auto minpass = [&](const float4* sp) {
#pragma unroll
    for (int j = 0; j < 8; j++) {
      float4 p = sp[j * 64 + lane];
      mnA = fminf(mnA, __builtin_fmaf(axA, p.x, __builtin_fmaf(ayA, p.y,
                       __builtin_fmaf(azA, p.z, p.w))));
      mnB = fminf(mnB, __builtin_fmaf(axB, p.x, __builtin_fmaf(ayB, p.y,
                       __builtin_fmaf(azB, p.z, p.w))));
    }
  };

  auto collect = [&](float e, float tau, unsigned* cq, int& cnt, unsigned idx) {
    bool pred = e <= tau;
    unsigned long long mask = __ballot(pred);
    if (mask) {                           // wave-uniform; most iters skip here
      int pos = cnt + lane_prefix(mask);
      if (pred && pos < 192) cq[pos] = idx;
      cnt += __popcll(mask);
    }
  };

  auto fused = [&](const float4* sp, unsigned base) {
#pragma unroll
    for (int j = 0; j < 8; j++) {
      float4 p = sp[j * 64 + lane];
      float ea = __builtin_fmaf(axA, p.x, __builtin_fmaf(ayA, p.y,
                 __builtin_fmaf(azA, p.z, p.w)));
      float eb = __builtin_fmaf(axB, p.x, __builtin_fmaf(ayB, p.y,
                 __builtin_fmaf(azB, p.z, p.w)));
      mnA = fminf(mnA, ea);
      mnB = fminf(mnB, eb);
      unsigned idx = base + j * 64 + lane;
      collect(ea, tauA, cqA, cntA, idx);
      collect(eb, tauB, cqB, cntB, idx);
    }
  };

  // ---- prologue: seed tau on first 1024 pts (two-pass over sc0/sc1) ----
  stage(spts[0], 0);
  __syncthreads();                       // sc0 visible
  stage(spts[1], 1);                     // in flight during minpass(sc0)
  minpass(spts[0]);
  __syncthreads();                       // sc1 visible
  minpass(spts[1]);
  tauA = tau16(mnA) + 0.01f;             // margin >> fma-vs-exact divergence
  tauB = tau16(mnB) + 0.01f;
  fused(spts[0], 0);
  fused(spts[1], 512);
  __syncthreads();                       // all waves done reading sc0/sc1
  stage(spts[0], 2);
  __syncthreads();                       // sc2 visible (single true stall)

  // ---- steady state: stage next sub-chunk, compute current, barrier ----
  for (int s = 2; s < 16; ++s) {
    if (s < 15) stage(spts[(s + 1) & 1], s + 1);
    fused(spts[s & 1], (unsigned)(s * 512));
    if (s == 3 || s == 7 || s == 11) {   // tighten tau at 2048/4096/6144 prefixes
      tauA = fminf(tauA, tau16(mnA) + 0.01f);
      tauB = fminf(tauB, tau16(mnB) + 0.01f);
    }
    __syncthreads();                     // drains vmcnt -> next buffer visible;
  }                                      // also protects the swap

  auto finalize = [&](ull* cb, int cnt, int gq,
                      float qx, float qy, float qz, float q2) {
    unsigned* cu = (unsigned*)cb;
    int E = cnt < 192 ? cnt : 192;            // E >= 16 guaranteed by prologue tau
    unsigned i0 = (lane < E) ? cu[lane] : 0u;
    unsigned i1 = (lane + 64 < E) ? cu[lane + 64] : 0u;
    unsigned i2 = (lane + 128 < E) ? cu[lane + 128] : 0u;
    float4 p0 = pb[i0];                       // parallel L2-hit loads
    float4 p1 = pb[i1];
    float4 p2 = pb[i2];
    ull k0 = ~0ull, k1 = ~0ull, k2 = ~0ull;
    if (lane < E)
      k0 = ((ull)flipf(d2_exact(qx, qy, qz, q2, p0)) << 32) | i0;
    if (lane + 64 < E)
      k1 = ((ull)flipf(d2_exact(qx, qy, qz, q2, p1)) << 32) | i1;
    if (lane + 128 < E)
      k2 = ((ull)flipf(d2_exact(qx, qy, qz, q2, p2)) << 32) | i2;
    // lane-min, then T = 16th-smallest lane-min (valid: E>=16 -> lanes 0..15
    // all hold a real k0). Every true top-16 key <= T; keys <= T live only in
    // the 16 lanes whose lane-min <= T -> at most 48 survivors.
    ull ml = k0 < k1 ? k0 : k1;
    if (k2 < ml) ml = k2;
    ull T = __shfl(bsort64(ml, lane), 15);
    // ballot-compact survivors into cb (u64 view; cu reads already consumed)
    int c2 = 0;
    {
      bool pr = k0 <= T; ull m = __ballot(pr);
      int pos = c2 + lane_prefix(m);
      if (pr) cb[pos] = k0;
      c2 += __popcll(m);
    }
    {
      bool pr = k1 <= T; ull m = __ballot(pr);
      int pos = c2 + lane_prefix(m);
      if (pr) cb[pos] = k1;
      c2 += __popcll(m);
    }
    {
      bool pr = k2 <= T; ull m = __ballot(pr);
      int pos = c2 + lane_prefix(m);
      if (pr) cb[pos] = k2;
      c2 += __popcll(m);
    }
    // wave-local RAW: lgkmcnt ordering suffices, no barrier
    ull kk = (lane < c2) ? cb[lane] : ~0ull;
    ull fin = bsort64(kk, lane);
    if (lane < 16) knn_out[(size_t)gq * 16 + lane] = (int)(unsigned)fin;
  };

  finalize(cbuf[wave * 2 + 0], cntA, qa,     A4.x, A4.y, A4.z, A4.w);
  finalize(cbuf[wave * 2 + 1], cntB, qa + 1, B4.x, B4.y, B4.z, B4.w);
}

// ---------------- K2: fused feature pipeline, 16 queries per block ----------------
// lane = channel. R7: w1 lives TRANSPOSED in LDS (w1T[c2][c], padded [64][65])
// instead of 64 VGPRs/lane. Diagnosis: the allocator caps this kernel near
// ~60 VGPRs, so the R2-R6 "w1s[64] in registers + asm pin" was silently
// spilled to scratch and reloaded 64x per matvec per query (the reason feat
// is ~125 us instead of ~25). w1T reads are lane-consecutive (conflict-free);
// the f0v read is a same-address broadcast. Live VGPRs now ~45 -> no spill.
__global__ void __launch_bounds__(256, 4) feat_kernel(
    const float4* __restrict__ pp, const float4* __restrict__ qp,
    const int* __restrict__ knn, const float* __restrict__ lfT,
    const float* __restrict__ w0, const float* __restrict__ b0,
    const float* __restrict__ g0, const float* __restrict__ be0,
    const float* __restrict__ m0, const float* __restrict__ v0,
    const float* __restrict__ w1, const float* __restrict__ b1,
    const float* __restrict__ g1, const float* __restrict__ be1,
    const float* __restrict__ m1, const float* __restrict__ v1,
    const float* __restrict__ w2, const float* __restrict__ b2,
    float* __restrict__ out) {
  __shared__ float w1T[64][65];        // 16.25 KB transposed w1 (pad kills conflicts)
  __shared__ float4 relbuf[4][16];
  __shared__ float4 f0v[4][64];
  __shared__ float outbuf[64][17];     // +1 pad breaks write-phase bank conflicts
  const int tid = threadIdx.x;
  const int lane = tid & 63;
  const int wave = tid >> 6;
  const int gq0 = blockIdx.x * 16;
  const int b = gq0 >> 13;

  // cooperative transpose of w1 (64x64) into LDS: 256 threads x 4 float4
  {
    const float4* w1f4 = (const float4*)w1;
#pragma unroll
    for (int k = 0; k < 4; k++) {
      int linear4 = tid + k * 256;           // float4 index
      int c = linear4 >> 4;                  // row (out channel)
      int c2 = (linear4 & 15) * 4;           // col (in channel)
      float4 t = w1f4[linear4];
      w1T[c2 + 0][c] = t.x;
      w1T[c2 + 1][c] = t.y;
      w1T[c2 + 2][c] = t.z;
      w1T[c2 + 3][c] = t.w;
    }
  }

  // BN folds (inline; fp order matches R0's fold_kernel)
  const float inv0 = g0[lane] / sqrtf(v0[lane] + 1e-5f);
  const float w00 = w0[lane * 3 + 0] * inv0;
  const float w01 = w0[lane * 3 + 1] * inv0;
  const float w02 = w0[lane * 3 + 2] * inv0;
  const float bb0 = (b0[lane] - m0[lane]) * inv0 + be0[lane];
  const float inv1 = g1[lane] / sqrtf(v1[lane] + 1e-5f);
  const float bb1 = (b1[lane] - m1[lane]) * inv1 + be1[lane];

  const float w2a = w2[lane], w2b = w2[64 + lane];
  const float bias2 = b2[0];
  const float4* pb = pp + ((size_t)b << 13);
  const float* lfb = lfT + (((size_t)b << 13)) * 64;

  __syncthreads();                       // w1T visible to all waves

  for (int qi = 0; qi < 4; qi++) {
    const int gq = gq0 + wave * 4 + qi;
    const float4 q4 = qp[gq];
    int nk = knn[(size_t)gq * 16 + (lane & 15)];
    float4 pk = pb[nk];
    if (lane < 16)
      relbuf[wave][lane] = make_float4(pk.x - q4.x, pk.y - q4.y, pk.z - q4.z, 0.0f);
    // wave-local RAW: lgkmcnt ordering suffices, no barrier

    float g = 0.0f, f0 = 0, f1 = 0, f2 = 0, f3 = 0;
#pragma unroll
    for (int k = 0; k < 16; k++) {
      float4 r = relbuf[wave][k];
      float y = fmaxf(0.0f, w00 * r.x + w01 * r.y + w02 * r.z + bb0);
      g = fmaxf(g, y);
      if (k == 0) f0 = y; else if (k == 1) f1 = y;
      else if (k == 2) f2 = y; else if (k == 3) f3 = y;
    }
    f0v[wave][lane] = make_float4(f0, f1, f2, f3);

    float a0 = 0, a1 = 0, a2 = 0, a3 = 0;
#pragma unroll
    for (int c2 = 0; c2 < 64; c2++) {
      float w = w1T[c2][lane];           // LDS, lane-consecutive: conflict-free
      float4 fb = f0v[wave][c2];         // LDS broadcast (same addr all lanes)
      a0 = fmaf(w, fb.x, a0); a1 = fmaf(w, fb.y, a1);
      a2 = fmaf(w, fb.z, a2); a3 = fmaf(w, fb.w, a3);
    }
    float r0 = fmaxf(0.0f, fmaf(a0, inv1, bb1));
    float r1 = fmaxf(0.0f, fmaf(a1, inv1, bb1));
    float r2 = fmaxf(0.0f, fmaf(a2, inv1, bb1));
    float r3 = fmaxf(0.0f, fmaf(a3, inv1, bb1));

    int i0 = __shfl(nk, 0), i1 = __shfl(nk, 1), i2 = __shfl(nk, 2), i3 = __shfl(nk, 3);
    float p0 = lfb[(size_t)i0 * 64 + lane];
    float p1 = lfb[(size_t)i1 * 64 + lane];
    float p2 = lfb[(size_t)i2 * 64 + lane];
    float p3 = lfb[(size_t)i3 * 64 + lane];

    float s0 = w2a * r0, s1 = w2a * r1, s2 = w2a * r2, s3 = w2a * r3, tg = w2b * g;
#pragma unroll
    for (int j = 1; j < 64; j <<= 1) {
      s0 += __shfl_xor(s0, j);
      s1 += __shfl_xor(s1, j);
      s2 += __shfl_xor(s2, j);
      s3 += __shfl_xor(s3, j);
      tg += __shfl_xor(tg, j);
    }
    float wk0 = 1.0f / (1.0f + __expf(-(s0 + tg + bias2)));
    float wk1 = 1.0f / (1.0f + __expf(-(s1 + tg + bias2)));
    float wk2 = 1.0f / (1.0f + __expf(-(s2 + tg + bias2)));
    float wk3 = 1.0f / (1.0f + __expf(-(s3 + tg + bias2)));

    float oc = ((1.0f - wk0) * r0 + wk0 * p0)
             + ((1.0f - wk1) * r1 + wk1 * p1)
             + ((1.0f - wk2) * r2 + wk2 * p2)
             + ((1.0f - wk3) * r3 + wk3 * p3);
    outbuf[lane][wave * 4 + qi] = oc;
  }
  __syncthreads();

  // coalesced output: thread t -> channel c = t>>2, 4 queries via float4
  int c = tid >> 2, j = tid & 3;
  float4 o4 = make_float4(outbuf[c][j * 4 + 0], outbuf[c][j * 4 + 1],
                          outbuf[c][j * 4 + 2], outbuf[c][j * 4 + 3]);
  *(float4*)(out + (((size_t)(b * 64 + c)) << 13) + (gq0 & (N_QRY - 1)) + j * 4) = o4;
}

extern "C" void kernel_launch(void* const* d_in, const int* in_sizes, int n_in,
                              void* d_out, int out_size, void* d_ws, size_t ws_size,
                              hipStream_t stream) {
  (void)in_sizes; (void)n_in; (void)out_size; (void)ws_size;
  const float* original_pts = (const float*)d_in[0];
  const float* query_pts   = (const float*)d_in[1];
  const float* local_feat  = (const float*)d_in[2];
  const float* w0 = (const float*)d_in[3];
  const float* b0 = (const float*)d_in[4];
  const float* g0 = (const float*)d_in[5];
  const float* be0 = (const float*)d_in[6];
  const float* m0 = (const float*)d_in[7];
  const float* v0 = (const float*)d_in[8];
  const float* w1 = (const float*)d_in[9];
  const float* b1 = (const float*)d_in[10];
  const float* g1 = (const float*)d_in[11];
  const float* be1 = (const float*)d_in[12];
  const float* m1 = (const float*)d_in[13];
  const float* v1 = (const float*)d_in[14];
  const float* w2 = (const float*)d_in[15];
  const float* b2 = (const float*)d_in[16];
  float* out = (float*)d_out;

  // workspace layout (16B aligned), total ~11.5 MB
  char* ws = (char*)d_ws;
  float4* pp  = (float4*)(ws);                 // 512 KB
  float4* qp  = (float4*)(ws + 524288);        // 512 KB
  float*  lfT = (float*)(ws + 1048576);        // 8 MB
  int*    knn = (int*)(ws + 9437184);          // 2 MB

  pack_pts<<<128, 256, 0, stream>>>(original_pts, pp, BATCH * M_PTS);
  pack_pts<<<128, 256, 0, stream>>>(query_pts, qp, BATCH * N_QRY);
  transpose_lf<<<512, 256, 0, stream>>>(local_feat, lfT);
  knn_kernel<<<4096, 256, 0, stream>>>(pp, qp, knn);
  feat_kernel<<<2048, 256, 0, stream>>>(pp, qp, knn, lfT,
                                        w0, b0, g0, be0, m0, v0,
                                        w1, b1, g1, be1, m1, v1,
                                        w2, b2, out);
}

// Round 8
// 252.783 us; speedup vs baseline: 1.1155x; 1.0097x over previous
//
#include <hip/hip_runtime.h>
#include <cstdint>

#define M_PTS 8192
#define N_QRY 8192
#define BATCH 4

typedef unsigned long long ull;

// ---------------- helpers ----------------
__device__ __forceinline__ float d2_exact(float qx, float qy, float qz, float q2, float4 p) {
#pragma clang fp contract(off)
  float dot = (qx * p.x + qy * p.y) + qz * p.z;   // reference op order, no fma
  return (q2 + p.w) - 2.0f * dot;
}

__device__ __forceinline__ unsigned flipf(float d) {
  unsigned u = __float_as_uint(d);
  return u ^ ((unsigned)((int)u >> 31) | 0x80000000u);   // order-preserving float->uint
}

__device__ __forceinline__ int lane_prefix(unsigned long long m) {
  return __builtin_amdgcn_mbcnt_hi((unsigned)(m >> 32),
         __builtin_amdgcn_mbcnt_lo((unsigned)m, 0));
}

__device__ __forceinline__ void ld_lds16(const float4* g, float4* l) {
  __builtin_amdgcn_global_load_lds((const __attribute__((address_space(1))) void*)g,
                                   (__attribute__((address_space(3))) void*)l, 16, 0, 0);
}

// Upper bound on the 16th-smallest of the 64 per-lane mins, via ballot bisection.
// Invariant: count(mn <= hi) >= 16 holds from init (hi = wave max -> 64). 10 steps
// give resolution (hi0-lo0)/1024; looseness only ADDS candidates, never drops one.
__device__ __forceinline__ float tau16(float mn) {
  float lo = mn, hi = mn;
#pragma unroll
  for (int j = 1; j < 64; j <<= 1) {
    lo = fminf(lo, __shfl_xor(lo, j));
    hi = fmaxf(hi, __shfl_xor(hi, j));
  }
#pragma unroll
  for (int it = 0; it < 10; it++) {
    float mid = 0.5f * (lo + hi);
    int cnt = __popcll(__ballot(mn <= mid));
    if (cnt >= 16) hi = mid; else lo = mid;   // wave-uniform
  }
  return hi;
}

// Full 64-lane ascending bitonic sort of u64 keys; lane i ends with the i-th
// smallest. Same network/orientation as the R0-verified rank16.
__device__ __forceinline__ ull bsort64(ull v, int lane) {
#pragma unroll
  for (int k = 2; k <= 64; k <<= 1) {
#pragma unroll
    for (int j = k >> 1; j >= 1; j >>= 1) {
      ull o = __shfl_xor(v, j);
      bool keepmin = (((lane & k) == 0) == ((lane & j) == 0));
      ull lo = v < o ? v : o;
      ull hi = v < o ? o : v;
      v = keepmin ? lo : hi;
    }
  }
  return v;
}

// ---------------- K0a: pack (x, y, z, x^2+y^2+z^2) ----------------
__global__ void pack_pts(const float* __restrict__ src, float4* __restrict__ dst, int total) {
#pragma clang fp contract(off)
  int i = blockIdx.x * 256 + threadIdx.x;
  if (i >= total) return;
  int b = i >> 13, m = i & (M_PTS - 1);
  const float* s = src + (size_t)b * 3 * M_PTS;
  float x = s[m], y = s[M_PTS + m], z = s[2 * M_PTS + m];
  float ss = (x * x + y * y) + z * z;   // matches jnp.sum(pts**2, axis=1) order
  dst[i] = make_float4(x, y, z, ss);
}

// ---------------- K0b: transpose local_feat (B,64,M) -> (B,M,64) ----------------
__global__ void transpose_lf(const float* __restrict__ lf, float* __restrict__ lfT) {
  __shared__ float tile[64][65];
  int bb = blockIdx.x >> 7;
  int m0 = (blockIdx.x & 127) << 6;
  int tm = threadIdx.x & 63;
  int tc = threadIdx.x >> 6;
  const float* src = lf + (size_t)bb * 64 * M_PTS;
#pragma unroll
  for (int i = 0; i < 16; i++) {
    int ch = i * 4 + tc;
    tile[ch][tm] = src[(size_t)ch * M_PTS + m0 + tm];
  }
  __syncthreads();
  float* dst = lfT + ((size_t)bb * M_PTS + m0) * 64;
#pragma unroll
  for (int i = 0; i < 16; i++) {
    int mm = i * 4 + tc;
    dst[(size_t)mm * 64 + tm] = tile[tm][mm];
  }
}

// ---------------- K1: exact KNN top-16, 2 queries per wave, 512-thr block ----------------
// R8: geometry change only — 8 waves/block (16 q/block, grid 2048). Same
// per-wave algorithm as R4/R7 (measured clean: VGPR 36, zero scratch).
// Why: R7 counters showed Occupancy 64% (20.5/32 waves) and VALUBusy 80%;
// with 512-thr blocks LDS is 16 KB spts + 12 KB cbuf = 28 KB -> 4 blocks x
// 8 waves = 32 waves/CU (100%), staging instrs/wave halve (1 ld_lds16 per
// sub-chunk), block-level overhead per query halves. Monotone prefix tau +
// dbuf staging + O(1)-sort finalize + exact rescore -> output bit-identical.
__global__ void __launch_bounds__(512, 8) knn_kernel(const float4* __restrict__ pp,
                                                     const float4* __restrict__ qp,
                                                     int* __restrict__ knn_out) {
  __shared__ float4 spts[2][512];        // 16 KB double-buffered point stage
  __shared__ ull cbuf[16][96];           // 12 KB cand buffers (per wave x 2 q; 192 u32 view)
  const int tid = threadIdx.x;
  const int lane = tid & 63;
  const int wave = tid >> 6;                      // 0..7
  const int b = blockIdx.x >> 9;                  // 512 blocks per batch
  const int qa = blockIdx.x * 16 + wave * 2;      // this wave's two queries
  const float4* pb = pp + ((size_t)b << 13);

  const float4 A4 = qp[qa];
  const float4 B4 = qp[qa + 1];
  const float axA = -2.0f * A4.x, ayA = -2.0f * A4.y, azA = -2.0f * A4.z;
  const float axB = -2.0f * B4.x, ayB = -2.0f * B4.y, azB = -2.0f * B4.z;

  int cntA = 0, cntB = 0;
  unsigned* cqA = (unsigned*)cbuf[wave * 2 + 0];
  unsigned* cqB = (unsigned*)cbuf[wave * 2 + 1];

  float mnA = 3.402823466e38f, mnB = 3.402823466e38f;
  float tauA = 0.0f, tauB = 0.0f;

  auto stage = [&](float4* dst, int s) {
    // 8 waves x 64 lanes cover the 512-pt sub-chunk with ONE ld_lds16 each
    const float4* g = pb + s * 512 + wave * 64 + lane;
    ld_lds16(g, &dst[wave * 64]);        // wave-uniform LDS base + lane*16
  };

  auto minpass = [&](const float4* sp) {
#pragma unroll
    for (int j = 0; j < 8; j++) {
      float4 p = sp[j * 64 + lane];
      mnA = fminf(mnA, __builtin_fmaf(axA, p.x, __builtin_fmaf(ayA, p.y,
                       __builtin_fmaf(azA, p.z, p.w))));
      mnB = fminf(mnB, __builtin_fmaf(axB, p.x, __builtin_fmaf(ayB, p.y,
                       __builtin_fmaf(azB, p.z, p.w))));
    }
  };

  auto collect = [&](float e, float tau, unsigned* cq, int& cnt, unsigned idx) {
    bool pred = e <= tau;
    unsigned long long mask = __ballot(pred);
    if (mask) {                           // wave-uniform; most iters skip here
      int pos = cnt + lane_prefix(mask);
      if (pred && pos < 192) cq[pos] = idx;
      cnt += __popcll(mask);
    }
  };

  auto fused = [&](const float4* sp, unsigned base) {
#pragma unroll
    for (int j = 0; j < 8; j++) {
      float4 p = sp[j * 64 + lane];
      float ea = __builtin_fmaf(axA, p.x, __builtin_fmaf(ayA, p.y,
                 __builtin_fmaf(azA, p.z, p.w)));
      float eb = __builtin_fmaf(axB, p.x, __builtin_fmaf(ayB, p.y,
                 __builtin_fmaf(azB, p.z, p.w)));
      mnA = fminf(mnA, ea);
      mnB = fminf(mnB, eb);
      unsigned idx = base + j * 64 + lane;
      collect(ea, tauA, cqA, cntA, idx);
      collect(eb, tauB, cqB, cntB, idx);
    }
  };

  // ---- prologue: seed tau on first 1024 pts (two-pass over sc0/sc1) ----
  stage(spts[0], 0);
  __syncthreads();                       // sc0 visible
  stage(spts[1], 1);                     // in flight during minpass(sc0)
  minpass(spts[0]);
  __syncthreads();                       // sc1 visible
  minpass(spts[1]);
  tauA = tau16(mnA) + 0.01f;             // margin >> fma-vs-exact divergence
  tauB = tau16(mnB) + 0.01f;
  fused(spts[0], 0);
  fused(spts[1], 512);
  __syncthreads();                       // all waves done reading sc0/sc1
  stage(spts[0], 2);
  __syncthreads();                       // sc2 visible (single true stall)

  // ---- steady state: stage next sub-chunk, compute current, barrier ----
  for (int s = 2; s < 16; ++s) {
    if (s < 15) stage(spts[(s + 1) & 1], s + 1);
    fused(spts[s & 1], (unsigned)(s * 512));
    if (s == 3 || s == 7 || s == 11) {   // tighten tau at 2048/4096/6144 prefixes
      tauA = fminf(tauA, tau16(mnA) + 0.01f);
      tauB = fminf(tauB, tau16(mnB) + 0.01f);
    }
    __syncthreads();                     // drains vmcnt -> next buffer visible;
  }                                      // also protects the swap

  auto finalize = [&](ull* cb, int cnt, int gq,
                      float qx, float qy, float qz, float q2) {
    unsigned* cu = (unsigned*)cb;
    int E = cnt < 192 ? cnt : 192;            // E >= 16 guaranteed by prologue tau
    unsigned i0 = (lane < E) ? cu[lane] : 0u;
    unsigned i1 = (lane + 64 < E) ? cu[lane + 64] : 0u;
    unsigned i2 = (lane + 128 < E) ? cu[lane + 128] : 0u;
    float4 p0 = pb[i0];                       // parallel L2-hit loads
    float4 p1 = pb[i1];
    float4 p2 = pb[i2];
    ull k0 = ~0ull, k1 = ~0ull, k2 = ~0ull;
    if (lane < E)
      k0 = ((ull)flipf(d2_exact(qx, qy, qz, q2, p0)) << 32) | i0;
    if (lane + 64 < E)
      k1 = ((ull)flipf(d2_exact(qx, qy, qz, q2, p1)) << 32) | i1;
    if (lane + 128 < E)
      k2 = ((ull)flipf(d2_exact(qx, qy, qz, q2, p2)) << 32) | i2;
    // lane-min, then T = 16th-smallest lane-min (valid: E>=16 -> lanes 0..15
    // all hold a real k0). Every true top-16 key <= T; keys <= T live only in
    // the 16 lanes whose lane-min <= T -> at most 48 survivors.
    ull ml = k0 < k1 ? k0 : k1;
    if (k2 < ml) ml = k2;
    ull T = __shfl(bsort64(ml, lane), 15);
    // ballot-compact survivors into cb (u64 view; cu reads already consumed)
    int c2 = 0;
    {
      bool pr = k0 <= T; ull m = __ballot(pr);
      int pos = c2 + lane_prefix(m);
      if (pr) cb[pos] = k0;
      c2 += __popcll(m);
    }
    {
      bool pr = k1 <= T; ull m = __ballot(pr);
      int pos = c2 + lane_prefix(m);
      if (pr) cb[pos] = k1;
      c2 += __popcll(m);
    }
    {
      bool pr = k2 <= T; ull m = __ballot(pr);
      int pos = c2 + lane_prefix(m);
      if (pr) cb[pos] = k2;
      c2 += __popcll(m);
    }
    // wave-local RAW: lgkmcnt ordering suffices, no barrier
    ull kk = (lane < c2) ? cb[lane] : ~0ull;
    ull fin = bsort64(kk, lane);
    if (lane < 16) knn_out[(size_t)gq * 16 + lane] = (int)(unsigned)fin;
  };

  finalize(cbuf[wave * 2 + 0], cntA, qa,     A4.x, A4.y, A4.z, A4.w);
  finalize(cbuf[wave * 2 + 1], cntB, qa + 1, B4.x, B4.y, B4.z, B4.w);
}

// ---------------- K2: fused feature pipeline, 32 queries per 512-thr block ----------------
// lane = channel; w1 transposed in LDS (conflict-free reads). R8: 8 waves/block
// (32 q/block, grid 1024) -> LDS 35.3 KB, 4 blocks x 8 waves = 32 waves/CU
// (100% occupancy vs ~50-75%); w1T transpose amortized over 2x queries.
// Also: lfb gathers issued right after nk arrives, so their latency hides
// under conv0 + the 64-iter matvec.
__global__ void __launch_bounds__(512, 8) feat_kernel(
    const float4* __restrict__ pp, const float4* __restrict__ qp,
    const int* __restrict__ knn, const float* __restrict__ lfT,
    const float* __restrict__ w0, const float* __restrict__ b0,
    const float* __restrict__ g0, const float* __restrict__ be0,
    const float* __restrict__ m0, const float* __restrict__ v0,
    const float* __restrict__ w1, const float* __restrict__ b1,
    const float* __restrict__ g1, const float* __restrict__ be1,
    const float* __restrict__ m1, const float* __restrict__ v1,
    const float* __restrict__ w2, const float* __restrict__ b2,
    float* __restrict__ out) {
  __shared__ float w1T[64][65];        // 16.6 KB transposed w1 (pad kills conflicts)
  __shared__ float4 relbuf[8][16];     // 2 KB
  __shared__ float4 f0v[8][64];        // 8 KB
  __shared__ float outbuf[64][33];     // 8.45 KB, +1 pad breaks bank conflicts
  const int tid = threadIdx.x;
  const int lane = tid & 63;
  const int wave = tid >> 6;           // 0..7
  const int gq0 = blockIdx.x * 32;
  const int b = gq0 >> 13;

  // cooperative transpose of w1 (64x64) into LDS: 512 threads x 2 float4
  {
    const float4* w1f4 = (const float4*)w1;
#pragma unroll
    for (int k = 0; k < 2; k++) {
      int linear4 = tid + k * 512;           // float4 index in [0,1024)
      int c = linear4 >> 4;                  // row (out channel)
      int c2 = (linear4 & 15) * 4;           // col (in channel)
      float4 t = w1f4[linear4];
      w1T[c2 + 0][c] = t.x;
      w1T[c2 + 1][c] = t.y;
      w1T[c2 + 2][c] = t.z;
      w1T[c2 + 3][c] = t.w;
    }
  }

  // BN folds (inline; fp order matches R0's fold_kernel)
  const float inv0 = g0[lane] / sqrtf(v0[lane] + 1e-5f);
  const float w00 = w0[lane * 3 + 0] * inv0;
  const float w01 = w0[lane * 3 + 1] * inv0;
  const float w02 = w0[lane * 3 + 2] * inv0;
  const float bb0 = (b0[lane] - m0[lane]) * inv0 + be0[lane];
  const float inv1 = g1[lane] / sqrtf(v1[lane] + 1e-5f);
  const float bb1 = (b1[lane] - m1[lane]) * inv1 + be1[lane];

  const float w2a = w2[lane], w2b = w2[64 + lane];
  const float bias2 = b2[0];
  const float4* pb = pp + ((size_t)b << 13);
  const float* lfb = lfT + (((size_t)b << 13)) * 64;

  __syncthreads();                       // w1T visible to all waves

  for (int qi = 0; qi < 4; qi++) {
    const int gq = gq0 + wave * 4 + qi;
    const float4 q4 = qp[gq];
    int nk = knn[(size_t)gq * 16 + (lane & 15)];
    float4 pk = pb[nk];
    // issue the lfb gathers NOW (they only need nk); latency hides under
    // conv0 + matvec below
    int i0 = __shfl(nk, 0), i1 = __shfl(nk, 1), i2 = __shfl(nk, 2), i3 = __shfl(nk, 3);
    float p0 = lfb[(size_t)i0 * 64 + lane];
    float p1 = lfb[(size_t)i1 * 64 + lane];
    float p2 = lfb[(size_t)i2 * 64 + lane];
    float p3 = lfb[(size_t)i3 * 64 + lane];

    if (lane < 16)
      relbuf[wave][lane] = make_float4(pk.x - q4.x, pk.y - q4.y, pk.z - q4.z, 0.0f);
    // wave-local RAW: lgkmcnt ordering suffices, no barrier

    float g = 0.0f, f0 = 0, f1 = 0, f2 = 0, f3 = 0;
#pragma unroll
    for (int k = 0; k < 16; k++) {
      float4 r = relbuf[wave][k];
      float y = fmaxf(0.0f, w00 * r.x + w01 * r.y + w02 * r.z + bb0);
      g = fmaxf(g, y);
      if (k == 0) f0 = y; else if (k == 1) f1 = y;
      else if (k == 2) f2 = y; else if (k == 3) f3 = y;
    }
    f0v[wave][lane] = make_float4(f0, f1, f2, f3);

    float a0 = 0, a1 = 0, a2 = 0, a3 = 0;
#pragma unroll
    for (int c2 = 0; c2 < 64; c2++) {
      float w = w1T[c2][lane];           // LDS, lane-consecutive: conflict-free
      float4 fb = f0v[wave][c2];         // LDS broadcast (same addr all lanes)
      a0 = fmaf(w, fb.x, a0); a1 = fmaf(w, fb.y, a1);
      a2 = fmaf(w, fb.z, a2); a3 = fmaf(w, fb.w, a3);
    }
    float r0 = fmaxf(0.0f, fmaf(a0, inv1, bb1));
    float r1 = fmaxf(0.0f, fmaf(a1, inv1, bb1));
    float r2 = fmaxf(0.0f, fmaf(a2, inv1, bb1));
    float r3 = fmaxf(0.0f, fmaf(a3, inv1, bb1));

    float s0 = w2a * r0, s1 = w2a * r1, s2 = w2a * r2, s3 = w2a * r3, tg = w2b * g;
#pragma unroll
    for (int j = 1; j < 64; j <<= 1) {
      s0 += __shfl_xor(s0, j);
      s1 += __shfl_xor(s1, j);
      s2 += __shfl_xor(s2, j);
      s3 += __shfl_xor(s3, j);
      tg += __shfl_xor(tg, j);
    }
    float wk0 = 1.0f / (1.0f + __expf(-(s0 + tg + bias2)));
    float wk1 = 1.0f / (1.0f + __expf(-(s1 + tg + bias2)));
    float wk2 = 1.0f / (1.0f + __expf(-(s2 + tg + bias2)));
    float wk3 = 1.0f / (1.0f + __expf(-(s3 + tg + bias2)));

    float oc = ((1.0f - wk0) * r0 + wk0 * p0)
             + ((1.0f - wk1) * r1 + wk1 * p1)
             + ((1.0f - wk2) * r2 + wk2 * p2)
             + ((1.0f - wk3) * r3 + wk3 * p3);
    outbuf[lane][wave * 4 + qi] = oc;
  }
  __syncthreads();

  // coalesced output: thread t -> channel c = t>>3, 8 query-groups via float4
  int c = tid >> 3, j = tid & 7;
  float4 o4 = make_float4(outbuf[c][j * 4 + 0], outbuf[c][j * 4 + 1],
                          outbuf[c][j * 4 + 2], outbuf[c][j * 4 + 3]);
  *(float4*)(out + (((size_t)(b * 64 + c)) << 13) + (gq0 & (N_QRY - 1)) + j * 4) = o4;
}

extern "C" void kernel_launch(void* const* d_in, const int* in_sizes, int n_in,
                              void* d_out, int out_size, void* d_ws, size_t ws_size,
                              hipStream_t stream) {
  (void)in_sizes; (void)n_in; (void)out_size; (void)ws_size;
  const float* original_pts = (const float*)d_in[0];
  const float* query_pts   = (const float*)d_in[1];
  const float* local_feat  = (const float*)d_in[2];
  const float* w0 = (const float*)d_in[3];
  const float* b0 = (const float*)d_in[4];
  const float* g0 = (const float*)d_in[5];
  const float* be0 = (const float*)d_in[6];
  const float* m0 = (const float*)d_in[7];
  const float* v0 = (const float*)d_in[8];
  const float* w1 = (const float*)d_in[9];
  const float* b1 = (const float*)d_in[10];
  const float* g1 = (const float*)d_in[11];
  const float* be1 = (const float*)d_in[12];
  const float* m1 = (const float*)d_in[13];
  const float* v1 = (const float*)d_in[14];
  const float* w2 = (const float*)d_in[15];
  const float* b2 = (const float*)d_in[16];
  float* out = (float*)d_out;

  // workspace layout (16B aligned), total ~11.5 MB
  char* ws = (char*)d_ws;
  float4* pp  = (float4*)(ws);                 // 512 KB
  float4* qp  = (float4*)(ws + 524288);        // 512 KB
  float*  lfT = (float*)(ws + 1048576);        // 8 MB
  int*    knn = (int*)(ws + 9437184);          // 2 MB

  pack_pts<<<128, 256, 0, stream>>>(original_pts, pp, BATCH * M_PTS);
  pack_pts<<<128, 256, 0, stream>>>(query_pts, qp, BATCH * N_QRY);
  transpose_lf<<<512, 256, 0, stream>>>(local_feat, lfT);
  knn_kernel<<<2048, 512, 0, stream>>>(pp, qp, knn);
  feat_kernel<<<1024, 512, 0, stream>>>(pp, qp, knn, lfT,
                                        w0, b0, g0, be0, m0, v0,
                                        w1, b1, g1, be1, m1, v1,
                                        w2, b2, out);
}